// Round 5
// baseline (289.679 us; speedup 1.0000x reference)
//
#include <hip/hip_runtime.h>

#define TLEN 512
#define HID  64

typedef _Float16 half8 __attribute__((ext_vector_type(8)));
typedef float    f32x4 __attribute__((ext_vector_type(4)));

__device__ __forceinline__ float rcp_fast(float x) { return __builtin_amdgcn_rcpf(x); }
__device__ __forceinline__ float sigmoid_fast(float x) { return rcp_fast(1.0f + __expf(-x)); }
__device__ __forceinline__ float tanh_fast(float x) { return 1.0f - 2.0f * rcp_fast(__expf(2.0f * x) + 1.0f); }

// 256 blocks x 8 waves; block owns 8 batch rows. Operand-swapped MFMA:
//   D[gaterow][batch] = W_hh_perm @ h^T   (16x16x32 f16, fp32 acc)
// A = W_hh with PERMUTED rows: M-row (4q+g) of wave w's tile tt is gate g of
// unit 8w+4tt+q. C/D layout col=lane&15 (batch), row=(lane>>4)*4+reg then puts
// ALL FOUR gates of (batch, unit) in one lane's 4 acc regs -> activation is
// fully in-register; no gates LDS round-trip (R4's main stall). h is
// double-buffered in LDS -> ONE barrier per step.
// Batch cols 8..15 of N are duplicates (bounded garbage; cols are independent
// in MFMA, never read back into real columns).
__global__ __launch_bounds__(512)
void lstm_mfma2(const float* __restrict__ x,
                const float* __restrict__ W_ih,
                const float* __restrict__ W_hh,
                const float* __restrict__ b_ih,
                const float* __restrict__ b_hh,
                const float* __restrict__ W_d,
                const float* __restrict__ b_d,
                float* __restrict__ out) {
    __shared__ __align__(16) float    xs[8][516];       // stride 516: 8 c-rows hit 8 banks
    __shared__ __align__(16) _Float16 hbuf[2][16][72];  // ping-pong h, stride 72 f16

    const int tid = threadIdx.x;
    const int L   = tid & 63;
    const int w   = tid >> 6;         // wave 0..7, owns units [8w, 8w+8)
    const int r0  = blockIdx.x * 8;

    // ---- stage x rows (float4) ----
    for (int i = tid; i < 8 * 128; i += 512) {
        const int r = i >> 7, t4 = (i & 127) * 4;
        *(float4*)&xs[r][t4] = *(const float4*)&x[(size_t)(r0 + r) * TLEN + t4];
    }
    // ---- zero both h buffers (h0 = 0; rows 8..15 stay finite) ----
    for (int i = tid; i < 2 * 16 * 72; i += 512)
        ((_Float16*)hbuf)[i] = (_Float16)0.0f;

    // ---- resident A-frags: A[m][k] m=L&15, k=32q+(L>>4)*8+i ----
    // perm: tile tt, m-row = 4*(m>>2)+... unit u = 8w+4tt+(m>>2), gate g = m&3
    half8 af[2][2];
    {
        const int m = L & 15;
        const int g = m & 3;
        const int kb = (L >> 4) * 8;
#pragma unroll
        for (int tt = 0; tt < 2; ++tt) {
            const int u = 8 * w + 4 * tt + (m >> 2);
            const float* row = &W_hh[(size_t)(g * HID + u) * HID];
#pragma unroll
            for (int q = 0; q < 2; ++q) {
                const float* p = row + 32 * q + kb;
                half8 hf;
#pragma unroll
                for (int i = 0; i < 8; ++i) hf[i] = (_Float16)p[i];
                af[tt][q] = hf;
            }
        }
    }

    // ---- per-lane activation params: (batch c, units u0,u1) ----
    const int c  = L & 15;            // c>=8: duplicate batch cols (waste lanes)
    const int u0 = 8 * w + (L >> 4);
    const int u1 = u0 + 4;
    float wih0[4], bia0[4], wih1[4], bia1[4];
#pragma unroll
    for (int g = 0; g < 4; ++g) {
        wih0[g] = W_ih[g * HID + u0];
        bia0[g] = b_ih[g * HID + u0] + b_hh[g * HID + u0];
        wih1[g] = W_ih[g * HID + u1];
        bia1[g] = b_ih[g * HID + u1] + b_hh[g * HID + u1];
    }

    const float* xrow = &xs[c & 7][0];
    const f32x4 zero = {0.0f, 0.0f, 0.0f, 0.0f};
    float c0 = 0.0f, c1 = 0.0f;
    int p = 0;

    __syncthreads();

    for (int t = 0; t < TLEN; ++t) {
        // B-frags: B[k][n] n=c, k=32q+(L>>4)*8+i  <- h of previous step
        const _Float16* hb = &hbuf[p][c][(L >> 4) * 8];
        const float xt = xrow[t];                 // issue early: LDS latency
        half8 b0 = *(const half8*)hb;
        half8 b1 = *(const half8*)(hb + 32);

        f32x4 d0 = __builtin_amdgcn_mfma_f32_16x16x32_f16(af[0][0], b0, zero, 0, 0, 0);
        f32x4 d1 = __builtin_amdgcn_mfma_f32_16x16x32_f16(af[1][0], b0, zero, 0, 0, 0);
        d0 = __builtin_amdgcn_mfma_f32_16x16x32_f16(af[0][1], b1, d0, 0, 0, 0);
        d1 = __builtin_amdgcn_mfma_f32_16x16x32_f16(af[1][1], b1, d1, 0, 0, 0);

        // unit u0: all 4 gates in d0[0..3] (i,f,g,o = regs 0..3 by perm)
        float ai = d0[0] + fmaf(xt, wih0[0], bia0[0]);
        float af_ = d0[1] + fmaf(xt, wih0[1], bia0[1]);
        float ag = d0[2] + fmaf(xt, wih0[2], bia0[2]);
        float ao = d0[3] + fmaf(xt, wih0[3], bia0[3]);
        float gi = sigmoid_fast(ai);
        float gf = sigmoid_fast(af_);
        float gg = tanh_fast(ag);
        float go = sigmoid_fast(ao);
        c0 = fmaf(gf, c0, gi * gg);
        const float h0 = go * tanh_fast(c0);

        // unit u1: gates in d1[0..3]
        ai  = d1[0] + fmaf(xt, wih1[0], bia1[0]);
        af_ = d1[1] + fmaf(xt, wih1[1], bia1[1]);
        ag  = d1[2] + fmaf(xt, wih1[2], bia1[2]);
        ao  = d1[3] + fmaf(xt, wih1[3], bia1[3]);
        gi = sigmoid_fast(ai);
        gf = sigmoid_fast(af_);
        gg = tanh_fast(ag);
        go = sigmoid_fast(ao);
        c1 = fmaf(gf, c1, gi * gg);
        const float h1 = go * tanh_fast(c1);

        hbuf[p ^ 1][c][u0] = (_Float16)h0;
        hbuf[p ^ 1][c][u1] = (_Float16)h1;
        __syncthreads();   // writes of step t+1's h done before anyone reads them
        p ^= 1;
    }

    // ---- epilogue: wave w reduces batch row w ----
    float pv = (float)hbuf[p][w][L] * W_d[L];
#pragma unroll
    for (int off = 32; off > 0; off >>= 1)
        pv += __shfl_xor(pv, off, 64);
    if (L == 0)
        out[r0 + w] = pv + b_d[0];
}

extern "C" void kernel_launch(void* const* d_in, const int* in_sizes, int n_in,
                              void* d_out, int out_size, void* d_ws, size_t ws_size,
                              hipStream_t stream) {
    const float* x    = (const float*)d_in[0];
    const float* W_ih = (const float*)d_in[1];
    const float* W_hh = (const float*)d_in[2];
    const float* b_ih = (const float*)d_in[3];
    const float* b_hh = (const float*)d_in[4];
    const float* W_d  = (const float*)d_in[5];
    const float* b_d  = (const float*)d_in[6];
    float* out = (float*)d_out;

    dim3 grid(256);    // 2048 / 8 batch rows per block
    dim3 block(512);   // 8 waves
    lstm_mfma2<<<grid, block, 0, stream>>>(x, W_ih, W_hh, b_ih, b_hh, W_d, b_d, out);
}

// Round 6
// 234.162 us; speedup vs baseline: 1.2371x; 1.2371x over previous
//
#include <hip/hip_runtime.h>

#define TLEN 512
#define HID  64

typedef _Float16 half8 __attribute__((ext_vector_type(8)));
typedef float    f32x4 __attribute__((ext_vector_type(4)));

__device__ __forceinline__ float rcp_fast(float x) { return __builtin_amdgcn_rcpf(x); }
__device__ __forceinline__ float sigmoid_fast(float x) { return rcp_fast(1.0f + __expf(-x)); }
__device__ __forceinline__ float tanh_fast(float x) { return 1.0f - 2.0f * rcp_fast(__expf(2.0f * x) + 1.0f); }

// 256 blocks x 8 waves; block owns 8 batch rows. Operand-swapped MFMA:
//   D[gaterow][batch] = W_hh_perm @ h^T   (16x16x32 f16, fp32 acc)
// A-rows permuted so wave w's tile tt, M-row 4q+g = gate g of unit 8w+4tt+q;
// C/D layout (col=lane&15=batch, row=(lane>>4)*4+reg) puts all 4 gates of one
// (batch,unit) in one lane's 4 acc regs.
//
// R6: LANE SPECIALIZATION. Batch cols 8..15 duplicate 0..7, so lanes c and
// c+8 hold identical d0/d1 (R5 wastefully ran identical activation chains in
// both). Now lane c activates unit u0 (d0), lane c+8 activates u1 (d1) --
// halves the VALU/transcendental issue load, which R5's counters showed is
// the bottleneck (VALUBusy 67%, MfmaUtil 11%). Each lane writes its h to
// hbuf rows b and b+8 (banks 4b+4w+d: all 32, 2 merged lanes/word).
__global__ __launch_bounds__(512)
void lstm_mfma3(const float* __restrict__ x,
                const float* __restrict__ W_ih,
                const float* __restrict__ W_hh,
                const float* __restrict__ b_ih,
                const float* __restrict__ b_hh,
                const float* __restrict__ W_d,
                const float* __restrict__ b_d,
                float* __restrict__ out) {
    __shared__ __align__(16) float    xs[8][516];       // stride 516: rows on distinct banks
    __shared__ __align__(16) _Float16 hbuf[2][16][72];  // ping-pong h, stride 72 f16

    const int tid = threadIdx.x;
    const int L   = tid & 63;
    const int w   = tid >> 6;         // wave 0..7, owns units [8w, 8w+8)
    const int r0  = blockIdx.x * 8;

    // ---- stage x rows (float4) ----
    for (int i = tid; i < 8 * 128; i += 512) {
        const int r = i >> 7, t4 = (i & 127) * 4;
        *(float4*)&xs[r][t4] = *(const float4*)&x[(size_t)(r0 + r) * TLEN + t4];
    }
    // ---- zero both h buffers (h0 = 0) ----
    for (int i = tid; i < 2 * 16 * 72; i += 512)
        ((_Float16*)hbuf)[i] = (_Float16)0.0f;

    // ---- resident A-frags: A[m][k], m=L&15, k=32q+(L>>4)*8+i ----
    // perm: tile tt -> unit 8w+4tt+(m>>2), gate m&3
    half8 af[2][2];
    {
        const int m = L & 15;
        const int g = m & 3;
        const int kb = (L >> 4) * 8;
#pragma unroll
        for (int tt = 0; tt < 2; ++tt) {
            const int uu = 8 * w + 4 * tt + (m >> 2);
            const float* row = &W_hh[(size_t)(g * HID + uu) * HID];
#pragma unroll
            for (int q = 0; q < 2; ++q) {
                const float* p = row + 32 * q + kb;
                half8 hf;
#pragma unroll
                for (int i = 0; i < 8; ++i) hf[i] = (_Float16)p[i];
                af[tt][q] = hf;
            }
        }
    }

    // ---- per-lane role: batch b, unit u; sel picks d0 (c<8) vs d1 (c>=8) ----
    const int c   = L & 15;
    const int b   = L & 7;
    const int sel = (L >> 3) & 1;
    const int u   = 8 * w + (L >> 4) + 4 * sel;

    float wih[4], bias[4];
#pragma unroll
    for (int g = 0; g < 4; ++g) {
        wih[g]  = W_ih[g * HID + u];
        bias[g] = b_ih[g * HID + u] + b_hh[g * HID + u];
    }

    const float* xrow = &xs[b][0];
    _Float16* hw0 = &hbuf[1][b][u];      // p^1 at t=0; toggled by 16*72 stride
    const f32x4 zero = {0.0f, 0.0f, 0.0f, 0.0f};
    float cst = 0.0f;
    int p = 0;

    __syncthreads();

    for (int t = 0; t < TLEN; ++t) {
        // B-frags: B[k][n] n=c, k=32q+(L>>4)*8+i  <- previous step's h
        const _Float16* hb = &hbuf[p][c][(L >> 4) * 8];
        const float xt = xrow[t];                 // issue early vs LDS latency
        half8 b0 = *(const half8*)hb;
        half8 b1 = *(const half8*)(hb + 32);

        f32x4 d0 = __builtin_amdgcn_mfma_f32_16x16x32_f16(af[0][0], b0, zero, 0, 0, 0);
        f32x4 d1 = __builtin_amdgcn_mfma_f32_16x16x32_f16(af[1][0], b0, zero, 0, 0, 0);
        d0 = __builtin_amdgcn_mfma_f32_16x16x32_f16(af[0][1], b1, d0, 0, 0, 0);
        d1 = __builtin_amdgcn_mfma_f32_16x16x32_f16(af[1][1], b1, d1, 0, 0, 0);

        const f32x4 d = sel ? d1 : d0;   // 4 cndmask

        const float ai = d[0] + fmaf(xt, wih[0], bias[0]);
        const float af_ = d[1] + fmaf(xt, wih[1], bias[1]);
        const float ag = d[2] + fmaf(xt, wih[2], bias[2]);
        const float ao = d[3] + fmaf(xt, wih[3], bias[3]);
        const float gi = sigmoid_fast(ai);
        const float gf = sigmoid_fast(af_);
        const float gg = tanh_fast(ag);
        const float go = sigmoid_fast(ao);
        cst = fmaf(gf, cst, gi * gg);
        const float hv = go * tanh_fast(cst);

        const _Float16 hh = (_Float16)hv;
        _Float16* hwp = hw0 + (p ^ 1) * 0 ;  // (kept simple: index directly below)
        hbuf[p ^ 1][b][u]     = hh;           // real col
        hbuf[p ^ 1][b + 8][u] = hh;           // duplicate col
        __syncthreads();
        p ^= 1;
    }

    // ---- epilogue: wave w reduces batch row w ----
    float pv = (float)hbuf[p][w][L] * W_d[L];
#pragma unroll
    for (int off = 32; off > 0; off >>= 1)
        pv += __shfl_xor(pv, off, 64);
    if (L == 0)
        out[r0 + w] = pv + b_d[0];
}

extern "C" void kernel_launch(void* const* d_in, const int* in_sizes, int n_in,
                              void* d_out, int out_size, void* d_ws, size_t ws_size,
                              hipStream_t stream) {
    const float* x    = (const float*)d_in[0];
    const float* W_ih = (const float*)d_in[1];
    const float* W_hh = (const float*)d_in[2];
    const float* b_ih = (const float*)d_in[3];
    const float* b_hh = (const float*)d_in[4];
    const float* W_d  = (const float*)d_in[5];
    const float* b_d  = (const float*)d_in[6];
    float* out = (float*)d_out;

    dim3 grid(256);    // 2048 / 8 batch rows per block
    dim3 block(512);   // 8 waves
    lstm_mfma3<<<grid, block, 0, stream>>>(x, W_ih, W_hh, b_ih, b_hh, W_d, b_d, out);
}